// Round 7
// baseline (216.817 us; speedup 1.0000x reference)
//
#include <hip/hip_runtime.h>
#include <math.h>

// Problem constants
#define DD 256
#define HH 8
#define AA 32
#define SS 512
#define BB 2
constexpr float BCONST      = 0.9f;
constexpr float ONE_MINUS_B = 0.1f;
constexpr float EPSF        = 1e-10f;
constexpr float SCALEF      = 0.0625f;   // 1/sqrt(256), exact power of 2
constexpr float FLTMAX      = 3.402823466e38f;

// Workspace layout (float offsets)
#define OFF_QKV    0
#define OFF_VP     786432
#define OFF_EW     1048576
#define OFF_PMIN   1310720
#define OFF_PMAX   1318912
#define OFF_VMIN   1327104
#define OFF_VRANGE 1327616
#define OFF_P      1328128

// Swizzled chunk buffer: row-major LD=32 floats, bank-quad ^= (row>>2)&7.
#define KB4(buf, row, col4) \
  (&(buf)[((row) << 5) | ((((col4) >> 2) ^ (((row) >> 2) & 7)) << 2)])

// ---------------------------------------------------------------------------
// Scalar-B GEMM: C[i][j] = dot(A[i,:], Wrow(j)), Wrow(j) = j<nsplit ? B0+j*K
// : B1+(j-nsplit)*K.  Block = 64 rows x 64 cols, 256 thr = 4 waves.
// lane = row; wave owns 16 cols. B window (4 cols x 8 k) is WAVE-UNIFORM
// (readfirstlane on wave id) -> lives in scalar/broadcast registers, zero
// LDS traffic for B. A: one b128 per 8 k per lane, reused across 16 cols
// (LDS reads/FMA = 1/64 vs 0.19 for the classic tile). Row pad +4 floats
// (quad stride == 1 mod 8) spreads the 64 lane reads evenly over 8 quads.
// ATOM: split-K partial, atomicAdd into (pre-zeroed) C.
// MM: V-blocks (j0>=512) reduce per-column min/max -> pminP/pmaxP[bx][d].
// ---------------------------------------------------------------------------
template<int KBT, bool MM, bool ATOM>
__global__ __launch_bounds__(256) void gemm_s(
    const float* __restrict__ A, const float* __restrict__ B0,
    const float* __restrict__ B1, int nsplit,
    float* __restrict__ C, int ldc, int lda, int K,
    float* __restrict__ pminP, float* __restrict__ pmaxP) {
  constexpr int LD = KBT + 4;
  __shared__ float A_lds[64 * LD];
  const int i0  = blockIdx.x * 64;
  const int j0  = blockIdx.y * 64;
  const int kb0 = ATOM ? blockIdx.z * KBT : 0;
  const int t   = threadIdx.x;
  const int l   = t & 63;

  // ---- stage A tile 64 x KBT (coalesced global, even-quad LDS writes)
  constexpr int TPR = KBT / 4;          // threads covering one row
  constexpr int RPP = 256 / TPR;        // rows per pass
  const int srow = t / TPR, scol = (t % TPR) * 4;
#pragma unroll
  for (int p = 0; p < 64 / RPP; ++p) {
    const int r = p * RPP + srow;
    float4 v = *(const float4*)(A + (size_t)(i0 + r) * lda + kb0 + scol);
    *(float4*)&A_lds[r * LD + scol] = v;
  }
  __syncthreads();

  const int w   = __builtin_amdgcn_readfirstlane(t >> 6);  // wave id, uniform
  const int j0w = j0 + w * 16;
  const float* Bw = (j0w < nsplit)
      ? (B0 + (size_t)j0w * (size_t)K + kb0)
      : (B1 + (size_t)(j0w - nsplit) * (size_t)K + kb0);

  float acc[16] = {};
#pragma unroll 2
  for (int k0 = 0; k0 < KBT; k0 += 8) {
    const float4 a0 = *(const float4*)&A_lds[l * LD + k0];
    const float4 a1 = *(const float4*)&A_lds[l * LD + k0 + 4];
    const float af[8] = {a0.x, a0.y, a0.z, a0.w, a1.x, a1.y, a1.z, a1.w};
#pragma unroll
    for (int jg = 0; jg < 4; ++jg) {
      const float* br = Bw + (size_t)(jg * 4) * K + k0;
      float bv[4][8];
#pragma unroll
      for (int c = 0; c < 4; ++c)
#pragma unroll
        for (int x = 0; x < 8; ++x) bv[c][x] = br[(size_t)c * K + x];
#pragma unroll
      for (int c = 0; c < 4; ++c)
#pragma unroll
        for (int x = 0; x < 8; ++x)
          acc[jg * 4 + c] += af[x] * bv[c][x];
    }
  }

  const size_t crow = (size_t)(i0 + l) * ldc + j0w;
  if (!ATOM) {
#pragma unroll
    for (int jg = 0; jg < 4; ++jg)
      *(float4*)(C + crow + jg * 4) =
          make_float4(acc[jg * 4], acc[jg * 4 + 1], acc[jg * 4 + 2], acc[jg * 4 + 3]);
  } else {
#pragma unroll
    for (int u = 0; u < 16; ++u) atomicAdd(C + crow + u, acc[u]);
  }

  if (MM && j0 >= 512) {               // V-column min/max via LDS transpose
    __syncthreads();                   // main-loop A_lds reads done
#pragma unroll
    for (int u = 0; u < 16; ++u) A_lds[l * LD + w * 16 + u] = acc[u];
    __syncthreads();
    if (t < 64) {
      float mn = A_lds[t], mx = mn;
#pragma unroll
      for (int r = 1; r < 64; ++r) {
        const float v = A_lds[r * LD + t];
        mn = fminf(mn, v);
        mx = fmaxf(mx, v);
      }
      const int bx = blockIdx.x;       // 0..15 (8 per batch)
      pminP[bx * 256 + (j0 - 512) + t] = mn;
      pmaxP[bx * 256 + (j0 - 512) + t] = mx;
    }
  }
}

// ---------------------------------------------------------------------------
// vp = expm1(p * log(v_norm)); also vmin / vrange per (b,d) and pw.
// Partials are now 8 per batch (row-tiles of 64).
// ---------------------------------------------------------------------------
__global__ __launch_bounds__(256) void vpk(
    const float* __restrict__ qkv, const float* __restrict__ pminP,
    const float* __restrict__ pmaxP, const float* __restrict__ p_param,
    float* __restrict__ vp, float* __restrict__ vminw,
    float* __restrict__ vrangew, float* __restrict__ pw) {
  const int blk = blockIdx.x;           // 0..1023
  const int b = blk >> 9, s = blk & 511;
  const int d = threadIdx.x;
  float mn = pminP[(b * 8) * 256 + d];
  float mx = pmaxP[(b * 8) * 256 + d];
#pragma unroll
  for (int c = 1; c < 8; ++c) {
    mn = fminf(mn, pminP[(b * 8 + c) * 256 + d]);
    mx = fmaxf(mx, pmaxP[(b * 8 + c) * 256 + d]);
  }
  float p = 50000.0f * tanhf(0.005f * p_param[d]) + 1.0f;
  if (p == 0.0f) p = 0.0001f;
  const float range = mx - mn + EPSF;
  const float v  = qkv[((size_t)(b * 512 + s)) * 768 + 512 + d];
  const float vn = (ONE_MINUS_B * (v - mn)) / range + BCONST;
  vp[(size_t)blk * 256 + d] = expm1f(p * logf(vn));
  if (s == 0) { vminw[b * 256 + d] = mn; vrangew[b * 256 + d] = range; }
  if (blk == 0) pw[d] = p;
}

// ---------------------------------------------------------------------------
// Fused attention (R6 version: XOR-swizzled kb, transposed scT LD=20,
// shfl+LDS epilogue). grid = (B*H, S/16); 256 threads.
// ---------------------------------------------------------------------------
__global__ __launch_bounds__(256) void attn_k(
    const float* __restrict__ qkv, const float* __restrict__ vp,
    const float* __restrict__ pw, const float* __restrict__ vminw,
    const float* __restrict__ vrangew, float* __restrict__ ew) {
  __shared__ float qs[16][36];
  __shared__ float scT[512 * 20];      // [k][q] scores -> unnormalized e
  __shared__ float kb[256 * 32];       // swizzled K / VP chunk (reused: part2)
  __shared__ float red[16][17];        // [q][0..15]=partials, [q][16]=T
  const int bh  = blockIdx.x;
  const int b   = bh >> 3, h = bh & 7;
  const int q0g = blockIdx.y * 16;
  const int t   = threadIdx.x;
  const int ldr = t >> 3, ldc4 = (t & 7) << 2;

  if (t < 128) {                       // q tile, fold in SCALE (exact *2^-4)
    const int q = t >> 3, c4 = (t & 7) << 2;
    float4 qv = *(const float4*)(qkv + ((size_t)(b * 512 + q0g + q)) * 768 + h * 32 + c4);
    qv.x *= SCALEF; qv.y *= SCALEF; qv.z *= SCALEF; qv.w *= SCALEF;
    *(float4*)&qs[q][c4] = qv;
  }

  float4 pk[8];
#pragma unroll
  for (int u = 0; u < 8; ++u)
    pk[u] = *(const float4*)(qkv + ((size_t)(b * 512 + ldr + 32 * u)) * 768 + 256 + h * 32 + ldc4);

  // ---- Phase 1: scores
  const int qg = t & 3;
  const int kg = t >> 2;
  for (int kc = 0; kc < 2; ++kc) {
    __syncthreads();
#pragma unroll
    for (int u = 0; u < 8; ++u) *(float4*)KB4(kb, ldr + 32 * u, ldc4) = pk[u];
    __syncthreads();
    if (kc == 0) {
#pragma unroll
      for (int u = 0; u < 8; ++u)
        pk[u] = *(const float4*)(qkv + ((size_t)(b * 512 + 256 + ldr + 32 * u)) * 768 + 256 + h * 32 + ldc4);
    } else {
#pragma unroll
      for (int u = 0; u < 8; ++u)
        pk[u] = *(const float4*)(vp + ((size_t)(b * 512 + ldr + 32 * u)) * 256 + h * 32 + ldc4);
    }
    float a2[4][4] = {};
#pragma unroll
    for (int kk = 0; kk < 32; kk += 4) {
      float4 qf[4], kf[4];
#pragma unroll
      for (int r = 0; r < 4; ++r) qf[r] = *(const float4*)&qs[qg * 4 + r][kk];
#pragma unroll
      for (int c = 0; c < 4; ++c) kf[c] = *(const float4*)KB4(kb, kg * 4 + c, kk);
#pragma unroll
      for (int r = 0; r < 4; ++r)
#pragma unroll
        for (int c = 0; c < 4; ++c)
          a2[r][c] += qf[r].x * kf[c].x + qf[r].y * kf[c].y +
                      qf[r].z * kf[c].z + qf[r].w * kf[c].w;
    }
#pragma unroll
    for (int c = 0; c < 4; ++c)
      *(float4*)&scT[(kc * 256 + kg * 4 + c) * 20 + qg * 4] =
          make_float4(a2[0][c], a2[1][c], a2[2][c], a2[3][c]);
  }
  __syncthreads();

  // ---- Phase 2: 2-pass softmax
  {
    const int q = t & 15, j = t >> 4;
    float m = -FLTMAX;
#pragma unroll
    for (int i = 0; i < 32; ++i) m = fmaxf(m, scT[(j * 32 + i) * 20 + q]);
    red[q][j] = m;
    __syncthreads();
    float rm = red[q][0];
#pragma unroll
    for (int jj = 1; jj < 16; ++jj) rm = fmaxf(rm, red[q][jj]);
    __syncthreads();
    float ls = 0.f;
#pragma unroll
    for (int i = 0; i < 32; ++i) {
      float e = __expf(scT[(j * 32 + i) * 20 + q] - rm);
      scT[(j * 32 + i) * 20 + q] = e;
      ls += e;
    }
    red[q][j] = ls;
    __syncthreads();
    if (j == 0) {
      float tot = 0.f;
#pragma unroll
      for (int jj = 0; jj < 16; ++jj) tot += red[q][jj];
      red[q][16] = tot;
    }
  }

  // ---- Phase 3
  float a3[4][4] = {};
  const int qg3 = t & 3;
  const int ag3 = (t >> 2) & 7;
  const int ks  = t >> 5;
  for (int kc = 0; kc < 2; ++kc) {
    __syncthreads();
#pragma unroll
    for (int u = 0; u < 8; ++u) *(float4*)KB4(kb, ldr + 32 * u, ldc4) = pk[u];
    __syncthreads();
    if (kc == 0) {
#pragma unroll
      for (int u = 0; u < 8; ++u)
        pk[u] = *(const float4*)(vp + ((size_t)(b * 512 + 256 + ldr + 32 * u)) * 256 + h * 32 + ldc4);
    }
#pragma unroll
    for (int g = 0; g < 8; ++g) {
#pragma unroll
      for (int c = 0; c < 4; ++c) {
        const int k = ks * 32 + g * 4 + c;
        const float4 sq = *(const float4*)&scT[(kc * 256 + k) * 20 + qg3 * 4];
        const float4 vf = *(const float4*)KB4(kb, k, ag3 * 4);
        a3[0][0] += sq.x * vf.x; a3[0][1] += sq.x * vf.y; a3[0][2] += sq.x * vf.z; a3[0][3] += sq.x * vf.w;
        a3[1][0] += sq.y * vf.x; a3[1][1] += sq.y * vf.y; a3[1][2] += sq.y * vf.z; a3[1][3] += sq.y * vf.w;
        a3[2][0] += sq.z * vf.x; a3[2][1] += sq.z * vf.y; a3[2][2] += sq.z * vf.z; a3[2][3] += sq.z * vf.w;
        a3[3][0] += sq.w * vf.x; a3[3][1] += sq.w * vf.y; a3[3][2] += sq.w * vf.z; a3[3][3] += sq.w * vf.w;
      }
    }
  }

#pragma unroll
  for (int r = 0; r < 4; ++r)
#pragma unroll
    for (int c = 0; c < 4; ++c)
      a3[r][c] += __shfl_xor(a3[r][c], 32);
  __syncthreads();
  float* part2 = &kb[0];               // [w4][520]
  if ((t & 32) == 0) {
    const int w = t >> 6;
#pragma unroll
    for (int r = 0; r < 4; ++r)
#pragma unroll
      for (int c = 0; c < 4; ++c)
        part2[w * 520 + (qg3 * 4 + r) * 32 + ag3 * 4 + c] = a3[r][c];
  }
  __syncthreads();
  {
    const int q = t >> 4, a = (t * 2) & 31;
    const float invT = 1.0f / red[q][16];
    float o2[2];
#pragma unroll
    for (int o = 0; o < 2; ++o) {
      const int ia = q * 32 + a + o;
      float s = part2[ia] + part2[520 + ia] + part2[1040 + ia] + part2[1560 + ia];
      s *= invT;
      const int d = h * 32 + a + o;
      const float p = pw[d];
      const float mean = log1pf(s);
      const float en = expf(mean / p);
      o2[o] = (en - BCONST) * vrangew[b * 256 + d] / ONE_MINUS_B + vminw[b * 256 + d];
    }
    *(float2*)(ew + ((size_t)(b * 512 + q0g + q)) * 256 + h * 32 + a) =
        make_float2(o2[0], o2[1]);
  }
}

// ---------------------------------------------------------------------------
extern "C" void kernel_launch(void* const* d_in, const int* in_sizes, int n_in,
                              void* d_out, int out_size, void* d_ws, size_t ws_size,
                              hipStream_t stream) {
  const float* ctx  = (const float*)d_in[0];
  const float* WQ   = (const float*)d_in[1];
  const float* WKV  = (const float*)d_in[2];
  const float* WOUT = (const float*)d_in[3];
  const float* PP   = (const float*)d_in[4];
  float* ws      = (float*)d_ws;
  float* qkv     = ws + OFF_QKV;
  float* vp      = ws + OFF_VP;
  float* ew      = ws + OFF_EW;
  float* pminP   = ws + OFF_PMIN;
  float* pmaxP   = ws + OFF_PMAX;
  float* vminw   = ws + OFF_VMIN;
  float* vrangew = ws + OFF_VRANGE;
  float* pw      = ws + OFF_P;
  float* out     = (float*)d_out;

  // Fused Q|K|V projection + V min/max partials (scalar-B, 64x64 tiles)
  gemm_s<256, true, false><<<dim3(16, 12), 256, 0, stream>>>(
      ctx, WQ, WKV, 256, qkv, 768, 256, 256, pminP, pmaxP);
  // expm1(p * log(v_norm)) + p vector + vmin/vrange
  vpk<<<1024, 256, 0, stream>>>(qkv, pminP, pmaxP, PP, vp, vminw, vrangew, pw);
  // Fused attention + power-mean epilogue
  attn_k<<<dim3(16, 32), 256, 0, stream>>>(qkv, vp, pw, vminw, vrangew, ew);
  // Output projection: scalar-B, split-K=4, atomic accumulate into zeroed out
  hipMemsetAsync(out, 0, (size_t)out_size * sizeof(float), stream);
  gemm_s<64, false, true><<<dim3(16, 4, 4), 256, 0, stream>>>(
      ew, WOUT, WOUT, 1 << 30, out, 256, 256, 256, nullptr, nullptr);
}

// Round 8
// 120.167 us; speedup vs baseline: 1.8043x; 1.8043x over previous
//
#include <hip/hip_runtime.h>
#include <math.h>

// Problem constants
#define DD 256
#define HH 8
#define AA 32
#define SS 512
#define BB 2
constexpr float BCONST      = 0.9f;
constexpr float ONE_MINUS_B = 0.1f;
constexpr float EPSF        = 1e-10f;
constexpr float SCALEF      = 0.0625f;   // 1/sqrt(256), exact power of 2
constexpr float FLTMAX      = 3.402823466e38f;

// Workspace layout (float offsets)
#define OFF_QKV    0
#define OFF_VP     786432
#define OFF_EW     1048576
#define OFF_PMIN   1310720
#define OFF_PMAX   1318912
#define OFF_VMIN   1327104
#define OFF_VRANGE 1327616
#define OFF_P      1328128

// Swizzled chunk buffer: row-major LD=32 floats, bank-quad ^= (row>>2)&7.
#define KB4(buf, row, col4) \
  (&(buf)[((row) << 5) | ((((col4) >> 2) ^ (((row) >> 2) & 7)) << 2)])

// ---------------------------------------------------------------------------
// Tiled fp32 GEMM (R6-proven): C[i][j] = dot(A[i,:K], Brow(j)).
// MM=true: V-column blocks also write per-row-tile min/max partials.
// ---------------------------------------------------------------------------
template<int TM, int TN, int RM, int RN, bool MM>
__global__ __launch_bounds__(256) void gemm_t(
    const float* __restrict__ A, const float* __restrict__ B0,
    const float* __restrict__ B1, int nsplit,
    float* __restrict__ C, int ldc, int K, int lda,
    float* __restrict__ pminP, float* __restrict__ pmaxP) {
  constexpr int LDT = 36;
  constexpr int CG  = TN / RN;
  constexpr int NA  = TM * 32 / 1024;
  constexpr int NB  = TN * 32 / 1024;
  __shared__ float As[TM][LDT];
  __shared__ float Bs[TN][LDT];
  const int i0 = blockIdx.x * TM;
  const int j0 = blockIdx.y * TN;
  const float* Bsrc = (j0 < nsplit) ? (B0 + (size_t)j0 * K)
                                    : (B1 + (size_t)(j0 - nsplit) * K);
  const int t  = threadIdx.x;
  const int lr = t >> 3;
  const int lc = (t & 7) << 2;
  const int tx = t % CG, ty = t / CG;

  float4 pa[NA], pb[NB];
#pragma unroll
  for (int u = 0; u < NA; ++u)
    pa[u] = *(const float4*)(A + (size_t)(i0 + lr + 32 * u) * lda + lc);
#pragma unroll
  for (int u = 0; u < NB; ++u)
    pb[u] = *(const float4*)(Bsrc + (size_t)(lr + 32 * u) * K + lc);

  float acc[RM][RN] = {};
  for (int k0 = 0; k0 < K; k0 += 32) {
    __syncthreads();
#pragma unroll
    for (int u = 0; u < NA; ++u) *(float4*)&As[lr + 32 * u][lc] = pa[u];
#pragma unroll
    for (int u = 0; u < NB; ++u) *(float4*)&Bs[lr + 32 * u][lc] = pb[u];
    __syncthreads();
    if (k0 + 32 < K) {
#pragma unroll
      for (int u = 0; u < NA; ++u)
        pa[u] = *(const float4*)(A + (size_t)(i0 + lr + 32 * u) * lda + k0 + 32 + lc);
#pragma unroll
      for (int u = 0; u < NB; ++u)
        pb[u] = *(const float4*)(Bsrc + (size_t)(lr + 32 * u) * K + k0 + 32 + lc);
    }
#pragma unroll
    for (int kk = 0; kk < 32; kk += 4) {
      float4 af[RM], bf[RN];
#pragma unroll
      for (int r = 0; r < RM; ++r) af[r] = *(const float4*)&As[ty * RM + r][kk];
#pragma unroll
      for (int c = 0; c < RN; ++c) bf[c] = *(const float4*)&Bs[tx + CG * c][kk];
#pragma unroll
      for (int r = 0; r < RM; ++r)
#pragma unroll
        for (int c = 0; c < RN; ++c)
          acc[r][c] += af[r].x * bf[c].x + af[r].y * bf[c].y +
                       af[r].z * bf[c].z + af[r].w * bf[c].w;
    }
  }
#pragma unroll
  for (int r = 0; r < RM; ++r)
#pragma unroll
    for (int c = 0; c < RN; ++c)
      C[(size_t)(i0 + ty * RM + r) * ldc + j0 + tx + CG * c] = acc[r][c];

  if (MM && j0 >= 512) {
    __syncthreads();
    float* mnb = &As[0][0];
    float* mxb = &Bs[0][0];
#pragma unroll
    for (int c = 0; c < RN; ++c) {
      float mn = acc[0][c], mx = acc[0][c];
#pragma unroll
      for (int r = 1; r < RM; ++r) {
        mn = fminf(mn, acc[r][c]);
        mx = fmaxf(mx, acc[r][c]);
      }
      mnb[(tx + CG * c) * 17 + ty] = mn;
      mxb[(tx + CG * c) * 17 + ty] = mx;
    }
    __syncthreads();
    if (t < TN) {
      float mn = mnb[t * 17], mx = mxb[t * 17];
#pragma unroll
      for (int i = 1; i < 16; ++i) {
        mn = fminf(mn, mnb[t * 17 + i]);
        mx = fmaxf(mx, mxb[t * 17 + i]);
      }
      const int bx = i0 >> 5;
      pminP[bx * 256 + (j0 - 512) + t] = mn;
      pmaxP[bx * 256 + (j0 - 512) + t] = mx;
    }
  }
}

// ---------------------------------------------------------------------------
// vp = expm1(p * log(v_norm)); also vmin / vrange per (b,d) and pw.
// ---------------------------------------------------------------------------
__global__ __launch_bounds__(256) void vpk(
    const float* __restrict__ qkv, const float* __restrict__ pminP,
    const float* __restrict__ pmaxP, const float* __restrict__ p_param,
    float* __restrict__ vp, float* __restrict__ vminw,
    float* __restrict__ vrangew, float* __restrict__ pw) {
  const int blk = blockIdx.x;           // 0..1023
  const int b = blk >> 9, s = blk & 511;
  const int d = threadIdx.x;
  float mn = pminP[(b * 16) * 256 + d];
  float mx = pmaxP[(b * 16) * 256 + d];
#pragma unroll
  for (int c = 1; c < 16; ++c) {
    mn = fminf(mn, pminP[(b * 16 + c) * 256 + d]);
    mx = fmaxf(mx, pmaxP[(b * 16 + c) * 256 + d]);
  }
  float p = 50000.0f * tanhf(0.005f * p_param[d]) + 1.0f;
  if (p == 0.0f) p = 0.0001f;
  const float range = mx - mn + EPSF;
  const float v  = qkv[((size_t)(b * 512 + s)) * 768 + 512 + d];
  const float vn = (ONE_MINUS_B * (v - mn)) / range + BCONST;
  vp[(size_t)blk * 256 + d] = expm1f(p * logf(vn));
  if (s == 0) { vminw[b * 256 + d] = mn; vrangew[b * 256 + d] = range; }
  if (blk == 0) pw[d] = p;
}

// ---------------------------------------------------------------------------
// Fused attention, CODE-SIZE-CONTROLLED build of the R6 kernel.
// Hypothesis H: the flat ~42 us across R4/R5/R6 is I-cache thrash from the
// ~5k-instruction fully-unrolled body (>32 KB code vs 32 KB I-cache), which
// matches VALUBusy 0.4-9% with no LDS/VMEM limiter. All inner loops are now
// partially unrolled (#pragma unroll 2/4) to keep the body under ~4 KB.
// Everything else (swizzled kb, transposed scT LD=20, shfl+LDS epilogue,
// numerics) is identical to R6.
// ---------------------------------------------------------------------------
__global__ __launch_bounds__(256) void attn_k(
    const float* __restrict__ qkv, const float* __restrict__ vp,
    const float* __restrict__ pw, const float* __restrict__ vminw,
    const float* __restrict__ vrangew, float* __restrict__ ew) {
  __shared__ float qs[16][36];
  __shared__ float scT[512 * 20];      // [k][q] scores -> unnormalized e
  __shared__ float kb[256 * 32];       // swizzled K / VP chunk (reused: part2)
  __shared__ float red[16][17];        // [q][0..15]=partials, [q][16]=T
  const int bh  = blockIdx.x;
  const int b   = bh >> 3, h = bh & 7;
  const int q0g = blockIdx.y * 16;
  const int t   = threadIdx.x;
  const int ldr = t >> 3, ldc4 = (t & 7) << 2;

  if (t < 128) {                       // q tile, fold in SCALE (exact *2^-4)
    const int q = t >> 3, c4 = (t & 7) << 2;
    float4 qv = *(const float4*)(qkv + ((size_t)(b * 512 + q0g + q)) * 768 + h * 32 + c4);
    qv.x *= SCALEF; qv.y *= SCALEF; qv.z *= SCALEF; qv.w *= SCALEF;
    *(float4*)&qs[q][c4] = qv;
  }

  float4 pk[8];
#pragma unroll 2
  for (int u = 0; u < 8; ++u)
    pk[u] = *(const float4*)(qkv + ((size_t)(b * 512 + ldr + 32 * u)) * 768 + 256 + h * 32 + ldc4);

  // ---- Phase 1: scores
  const int qg = t & 3;
  const int kg = t >> 2;
  for (int kc = 0; kc < 2; ++kc) {
    __syncthreads();
#pragma unroll 2
    for (int u = 0; u < 8; ++u) *(float4*)KB4(kb, ldr + 32 * u, ldc4) = pk[u];
    __syncthreads();
    if (kc == 0) {
#pragma unroll 2
      for (int u = 0; u < 8; ++u)
        pk[u] = *(const float4*)(qkv + ((size_t)(b * 512 + 256 + ldr + 32 * u)) * 768 + 256 + h * 32 + ldc4);
    } else {
#pragma unroll 2
      for (int u = 0; u < 8; ++u)
        pk[u] = *(const float4*)(vp + ((size_t)(b * 512 + ldr + 32 * u)) * 256 + h * 32 + ldc4);
    }
    float a2[4][4] = {};
#pragma unroll 2
    for (int kk = 0; kk < 32; kk += 4) {
      float4 qf[4], kf[4];
#pragma unroll
      for (int r = 0; r < 4; ++r) qf[r] = *(const float4*)&qs[qg * 4 + r][kk];
#pragma unroll
      for (int c = 0; c < 4; ++c) kf[c] = *(const float4*)KB4(kb, kg * 4 + c, kk);
#pragma unroll
      for (int r = 0; r < 4; ++r)
#pragma unroll
        for (int c = 0; c < 4; ++c)
          a2[r][c] += qf[r].x * kf[c].x + qf[r].y * kf[c].y +
                      qf[r].z * kf[c].z + qf[r].w * kf[c].w;
    }
#pragma unroll
    for (int c = 0; c < 4; ++c)
      *(float4*)&scT[(kc * 256 + kg * 4 + c) * 20 + qg * 4] =
          make_float4(a2[0][c], a2[1][c], a2[2][c], a2[3][c]);
  }
  __syncthreads();

  // ---- Phase 2: 2-pass softmax (rolled scans)
  {
    const int q = t & 15, j = t >> 4;
    float m = -FLTMAX;
#pragma unroll 4
    for (int i = 0; i < 32; ++i) m = fmaxf(m, scT[(j * 32 + i) * 20 + q]);
    red[q][j] = m;
    __syncthreads();
    float rm = red[q][0];
#pragma unroll 4
    for (int jj = 1; jj < 16; ++jj) rm = fmaxf(rm, red[q][jj]);
    __syncthreads();
    float ls = 0.f;
#pragma unroll 4
    for (int i = 0; i < 32; ++i) {
      float e = __expf(scT[(j * 32 + i) * 20 + q] - rm);
      scT[(j * 32 + i) * 20 + q] = e;
      ls += e;
    }
    red[q][j] = ls;
    __syncthreads();
    if (j == 0) {
      float tot = 0.f;
#pragma unroll 4
      for (int jj = 0; jj < 16; ++jj) tot += red[q][jj];
      red[q][16] = tot;
    }
  }

  // ---- Phase 3
  float a3[4][4] = {};
  const int qg3 = t & 3;
  const int ag3 = (t >> 2) & 7;
  const int ks  = t >> 5;
  for (int kc = 0; kc < 2; ++kc) {
    __syncthreads();
#pragma unroll 2
    for (int u = 0; u < 8; ++u) *(float4*)KB4(kb, ldr + 32 * u, ldc4) = pk[u];
    __syncthreads();
    if (kc == 0) {
#pragma unroll 2
      for (int u = 0; u < 8; ++u)
        pk[u] = *(const float4*)(vp + ((size_t)(b * 512 + 256 + ldr + 32 * u)) * 256 + h * 32 + ldc4);
    }
#pragma unroll 2
    for (int g = 0; g < 8; ++g) {
#pragma unroll
      for (int c = 0; c < 4; ++c) {
        const int k = ks * 32 + g * 4 + c;
        const float4 sq = *(const float4*)&scT[(kc * 256 + k) * 20 + qg3 * 4];
        const float4 vf = *(const float4*)KB4(kb, k, ag3 * 4);
        a3[0][0] += sq.x * vf.x; a3[0][1] += sq.x * vf.y; a3[0][2] += sq.x * vf.z; a3[0][3] += sq.x * vf.w;
        a3[1][0] += sq.y * vf.x; a3[1][1] += sq.y * vf.y; a3[1][2] += sq.y * vf.z; a3[1][3] += sq.y * vf.w;
        a3[2][0] += sq.z * vf.x; a3[2][1] += sq.z * vf.y; a3[2][2] += sq.z * vf.z; a3[2][3] += sq.z * vf.w;
        a3[3][0] += sq.w * vf.x; a3[3][1] += sq.w * vf.y; a3[3][2] += sq.w * vf.z; a3[3][3] += sq.w * vf.w;
      }
    }
  }

#pragma unroll
  for (int r = 0; r < 4; ++r)
#pragma unroll
    for (int c = 0; c < 4; ++c)
      a3[r][c] += __shfl_xor(a3[r][c], 32);
  __syncthreads();
  float* part2 = &kb[0];               // [w4][520]
  if ((t & 32) == 0) {
    const int w = t >> 6;
#pragma unroll
    for (int r = 0; r < 4; ++r)
#pragma unroll
      for (int c = 0; c < 4; ++c)
        part2[w * 520 + (qg3 * 4 + r) * 32 + ag3 * 4 + c] = a3[r][c];
  }
  __syncthreads();
  {
    const int q = t >> 4, a = (t * 2) & 31;
    const float invT = 1.0f / red[q][16];
    float o2[2];
#pragma unroll
    for (int o = 0; o < 2; ++o) {
      const int ia = q * 32 + a + o;
      float s = part2[ia] + part2[520 + ia] + part2[1040 + ia] + part2[1560 + ia];
      s *= invT;
      const int d = h * 32 + a + o;
      const float p = pw[d];
      const float mean = log1pf(s);         // log(sum sm * v^p), robust near 1
      const float en = expf(mean / p);      // robust as p -> 0
      o2[o] = (en - BCONST) * vrangew[b * 256 + d] / ONE_MINUS_B + vminw[b * 256 + d];
    }
    *(float2*)(ew + ((size_t)(b * 512 + q0g + q)) * 256 + h * 32 + a) =
        make_float2(o2[0], o2[1]);
  }
}

// ---------------------------------------------------------------------------
extern "C" void kernel_launch(void* const* d_in, const int* in_sizes, int n_in,
                              void* d_out, int out_size, void* d_ws, size_t ws_size,
                              hipStream_t stream) {
  const float* ctx  = (const float*)d_in[0];
  const float* WQ   = (const float*)d_in[1];
  const float* WKV  = (const float*)d_in[2];
  const float* WOUT = (const float*)d_in[3];
  const float* PP   = (const float*)d_in[4];
  float* ws      = (float*)d_ws;
  float* qkv     = ws + OFF_QKV;
  float* vp      = ws + OFF_VP;
  float* ew      = ws + OFF_EW;
  float* pminP   = ws + OFF_PMIN;
  float* pmaxP   = ws + OFF_PMAX;
  float* vminw   = ws + OFF_VMIN;
  float* vrangew = ws + OFF_VRANGE;
  float* pw      = ws + OFF_P;
  float* out     = (float*)d_out;

  // Fused Q|K|V projection + V min/max partials: 1024x768x256, 32x64 tiles
  gemm_t<32, 64, 2, 4, true><<<dim3(32, 12), 256, 0, stream>>>(
      ctx, WQ, WKV, 256, qkv, 768, 256, 256, pminP, pmaxP);
  // expm1(p * log(v_norm)) + p vector + vmin/vrange
  vpk<<<1024, 256, 0, stream>>>(qkv, pminP, pmaxP, PP, vp, vminw, vrangew, pw);
  // Fused attention + power-mean epilogue (code-size-controlled)
  attn_k<<<dim3(16, 32), 256, 0, stream>>>(qkv, vp, pw, vminw, vrangew, ew);
  // Output projection: 1024x256x256, 32x32 tiles
  gemm_t<32, 32, 2, 2, false><<<dim3(32, 8), 256, 0, stream>>>(
      ew, WOUT, WOUT, 1 << 30, out, 256, 256, 256, nullptr, nullptr);
}

// Round 9
// 109.781 us; speedup vs baseline: 1.9750x; 1.0946x over previous
//
#include <hip/hip_runtime.h>
#include <math.h>

// Problem constants
#define DD 256
#define HH 8
#define AA 32
#define SS 512
#define BB 2
constexpr float BCONST      = 0.9f;
constexpr float ONE_MINUS_B = 0.1f;
constexpr float EPSF        = 1e-10f;
constexpr float SCALEF      = 0.0625f;   // 1/sqrt(256), exact power of 2
constexpr float FLTMAX      = 3.402823466e38f;

// Workspace layout (float offsets)
#define OFF_QKV    0
#define OFF_VP     786432
#define OFF_EW     1048576
#define OFF_PMIN   1310720
#define OFF_PMAX   1318912
#define OFF_VMIN   1327104
#define OFF_VRANGE 1327616
#define OFF_P      1328128

// Swizzled chunk buffer: row-major LD=32 floats, bank-quad ^= (row>>2)&7.
#define KB4(buf, row, col4) \
  (&(buf)[((row) << 5) | ((((col4) >> 2) ^ (((row) >> 2) & 7)) << 2)])

// ---------------------------------------------------------------------------
// Tiled fp32 GEMM (R6/R8-proven): C[i][j] = dot(A[i,:K], Brow(j)).
// MM=true: V-column blocks also write per-row-tile min/max partials.
// ---------------------------------------------------------------------------
template<int TM, int TN, int RM, int RN, bool MM>
__global__ __launch_bounds__(256) void gemm_t(
    const float* __restrict__ A, const float* __restrict__ B0,
    const float* __restrict__ B1, int nsplit,
    float* __restrict__ C, int ldc, int K, int lda,
    float* __restrict__ pminP, float* __restrict__ pmaxP) {
  constexpr int LDT = 36;
  constexpr int CG  = TN / RN;
  constexpr int NA  = TM * 32 / 1024;
  constexpr int NB  = TN * 32 / 1024;
  __shared__ float As[TM][LDT];
  __shared__ float Bs[TN][LDT];
  const int i0 = blockIdx.x * TM;
  const int j0 = blockIdx.y * TN;
  const float* Bsrc = (j0 < nsplit) ? (B0 + (size_t)j0 * K)
                                    : (B1 + (size_t)(j0 - nsplit) * K);
  const int t  = threadIdx.x;
  const int lr = t >> 3;
  const int lc = (t & 7) << 2;
  const int tx = t % CG, ty = t / CG;

  float4 pa[NA], pb[NB];
#pragma unroll
  for (int u = 0; u < NA; ++u)
    pa[u] = *(const float4*)(A + (size_t)(i0 + lr + 32 * u) * lda + lc);
#pragma unroll
  for (int u = 0; u < NB; ++u)
    pb[u] = *(const float4*)(Bsrc + (size_t)(lr + 32 * u) * K + lc);

  float acc[RM][RN] = {};
  for (int k0 = 0; k0 < K; k0 += 32) {
    __syncthreads();
#pragma unroll
    for (int u = 0; u < NA; ++u) *(float4*)&As[lr + 32 * u][lc] = pa[u];
#pragma unroll
    for (int u = 0; u < NB; ++u) *(float4*)&Bs[lr + 32 * u][lc] = pb[u];
    __syncthreads();
    if (k0 + 32 < K) {
#pragma unroll
      for (int u = 0; u < NA; ++u)
        pa[u] = *(const float4*)(A + (size_t)(i0 + lr + 32 * u) * lda + k0 + 32 + lc);
#pragma unroll
      for (int u = 0; u < NB; ++u)
        pb[u] = *(const float4*)(Bsrc + (size_t)(lr + 32 * u) * K + k0 + 32 + lc);
    }
#pragma unroll
    for (int kk = 0; kk < 32; kk += 4) {
      float4 af[RM], bf[RN];
#pragma unroll
      for (int r = 0; r < RM; ++r) af[r] = *(const float4*)&As[ty * RM + r][kk];
#pragma unroll
      for (int c = 0; c < RN; ++c) bf[c] = *(const float4*)&Bs[tx + CG * c][kk];
#pragma unroll
      for (int r = 0; r < RM; ++r)
#pragma unroll
        for (int c = 0; c < RN; ++c)
          acc[r][c] += af[r].x * bf[c].x + af[r].y * bf[c].y +
                       af[r].z * bf[c].z + af[r].w * bf[c].w;
    }
  }
#pragma unroll
  for (int r = 0; r < RM; ++r)
#pragma unroll
    for (int c = 0; c < RN; ++c)
      C[(size_t)(i0 + ty * RM + r) * ldc + j0 + tx + CG * c] = acc[r][c];

  if (MM && j0 >= 512) {
    __syncthreads();
    float* mnb = &As[0][0];
    float* mxb = &Bs[0][0];
#pragma unroll
    for (int c = 0; c < RN; ++c) {
      float mn = acc[0][c], mx = acc[0][c];
#pragma unroll
      for (int r = 1; r < RM; ++r) {
        mn = fminf(mn, acc[r][c]);
        mx = fmaxf(mx, acc[r][c]);
      }
      mnb[(tx + CG * c) * 17 + ty] = mn;
      mxb[(tx + CG * c) * 17 + ty] = mx;
    }
    __syncthreads();
    if (t < TN) {
      float mn = mnb[t * 17], mx = mxb[t * 17];
#pragma unroll
      for (int i = 1; i < 16; ++i) {
        mn = fminf(mn, mnb[t * 17 + i]);
        mx = fmaxf(mx, mxb[t * 17 + i]);
      }
      const int bx = i0 >> 5;
      pminP[bx * 256 + (j0 - 512) + t] = mn;
      pmaxP[bx * 256 + (j0 - 512) + t] = mx;
    }
  }
}

// ---------------------------------------------------------------------------
// vp = expm1(p * log(v_norm)); also vmin / vrange per (b,d) and pw.
// ---------------------------------------------------------------------------
__global__ __launch_bounds__(256) void vpk(
    const float* __restrict__ qkv, const float* __restrict__ pminP,
    const float* __restrict__ pmaxP, const float* __restrict__ p_param,
    float* __restrict__ vp, float* __restrict__ vminw,
    float* __restrict__ vrangew, float* __restrict__ pw) {
  const int blk = blockIdx.x;           // 0..1023
  const int b = blk >> 9, s = blk & 511;
  const int d = threadIdx.x;
  float mn = pminP[(b * 16) * 256 + d];
  float mx = pmaxP[(b * 16) * 256 + d];
#pragma unroll
  for (int c = 1; c < 16; ++c) {
    mn = fminf(mn, pminP[(b * 16 + c) * 256 + d]);
    mx = fmaxf(mx, pmaxP[(b * 16 + c) * 256 + d]);
  }
  float p = 50000.0f * tanhf(0.005f * p_param[d]) + 1.0f;
  if (p == 0.0f) p = 0.0001f;
  const float range = mx - mn + EPSF;
  const float v  = qkv[((size_t)(b * 512 + s)) * 768 + 512 + d];
  const float vn = (ONE_MINUS_B * (v - mn)) / range + BCONST;
  vp[(size_t)blk * 256 + d] = expm1f(p * logf(vn));
  if (s == 0) { vminw[b * 256 + d] = mn; vrangew[b * 256 + d] = range; }
  if (blk == 0) pw[d] = p;
}

// ---------------------------------------------------------------------------
// Fused attention v3: 32 queries/block, whole 512-k panel staged once.
// Structurally LDS-lean micro-tiles:
//   Phase 1: 8q x 8k per thread (qg = WAVE id -> qs reads are wave-uniform
//            broadcasts); 16 b128 per 256 FMA (was 8 per 64).
//   Phase 3: 8q x 4a per thread, 8-way k-split; 12 b128 per 128 FMA.
// sc[q][k], LD=516 (quad stride 1 mod 8). kb XOR-swizzled. 1 block/CU.
// grid = (S/32, B*H); 256 threads.
// ---------------------------------------------------------------------------
__global__ __launch_bounds__(256) void attn_k(
    const float* __restrict__ qkv, const float* __restrict__ vp,
    const float* __restrict__ pw, const float* __restrict__ vminw,
    const float* __restrict__ vrangew, float* __restrict__ ew) {
  __shared__ float qs[32][36];
  __shared__ float sc[32 * 516];       // [q][k] scores -> unnormalized e
  __shared__ float kb[512 * 32];       // swizzled K / VP panel (reused: part)
  __shared__ float red[32][9];         // [q][0..7]=partials, [q][8]=T
  const int bh  = blockIdx.y;
  const int b   = bh >> 3, h = bh & 7;
  const int q0g = blockIdx.x * 32;
  const int t   = threadIdx.x;
  const int srow = t >> 3, scol4 = (t & 7) << 2;

  // q tile (32 x 32), fold in SCALE (exact *2^-4)
  {
    const int q = t >> 3, c4 = (t & 7) << 2;
    float4 qv = *(const float4*)(qkv + ((size_t)(b * 512 + q0g + q)) * 768 + h * 32 + c4);
    qv.x *= SCALEF; qv.y *= SCALEF; qv.z *= SCALEF; qv.w *= SCALEF;
    *(float4*)&qs[q][c4] = qv;
  }
  // stage FULL K panel (512 rows)
#pragma unroll 8
  for (int u = 0; u < 16; ++u) {
    const int r = srow + 32 * u;
    float4 v = *(const float4*)(qkv + ((size_t)(b * 512 + r)) * 768 + 256 + h * 32 + scol4);
    *(float4*)KB4(kb, r, scol4) = v;
  }
  __syncthreads();

  // ---- Phase 1: scores 32q x 512k; thread = 8q (qgw+4r) x 8k (2 half-tiles)
  {
    const int qgw = t >> 6;            // wave id: wave-uniform q group
    const int kg  = t & 63;            // k cols kg*4..+3 and 256+kg*4..+3
    float s8[8][8] = {};
#pragma unroll 2
    for (int kk = 0; kk < 32; kk += 4) {
      float4 qf[8], kf1[4], kf2[4];
#pragma unroll
      for (int r = 0; r < 8; ++r) qf[r] = *(const float4*)&qs[qgw + 4 * r][kk];
#pragma unroll
      for (int c = 0; c < 4; ++c) {
        kf1[c] = *(const float4*)KB4(kb, kg * 4 + c, kk);
        kf2[c] = *(const float4*)KB4(kb, 256 + kg * 4 + c, kk);
      }
#pragma unroll
      for (int r = 0; r < 8; ++r)
#pragma unroll
        for (int c = 0; c < 4; ++c) {
          s8[r][c]     += qf[r].x * kf1[c].x + qf[r].y * kf1[c].y +
                          qf[r].z * kf1[c].z + qf[r].w * kf1[c].w;
          s8[r][4 + c] += qf[r].x * kf2[c].x + qf[r].y * kf2[c].y +
                          qf[r].z * kf2[c].z + qf[r].w * kf2[c].w;
        }
    }
#pragma unroll
    for (int r = 0; r < 8; ++r) {
      const int rq = qgw + 4 * r;
      *(float4*)&sc[rq * 516 + kg * 4] =
          make_float4(s8[r][0], s8[r][1], s8[r][2], s8[r][3]);
      *(float4*)&sc[rq * 516 + 256 + kg * 4] =
          make_float4(s8[r][4], s8[r][5], s8[r][6], s8[r][7]);
    }
  }
  __syncthreads();

  // ---- Phase 2: 2-pass softmax; thread (q, j) owns k in [64j, 64j+64)
  {
    const int q = t & 31, j = t >> 5;
    float m = -FLTMAX;
#pragma unroll 4
    for (int g = 0; g < 16; ++g) {
      float4 x = *(const float4*)&sc[q * 516 + j * 64 + 4 * g];
      m = fmaxf(m, fmaxf(fmaxf(x.x, x.y), fmaxf(x.z, x.w)));
    }
    red[q][j] = m;
    __syncthreads();
    float rm = red[q][0];
#pragma unroll
    for (int jj = 1; jj < 8; ++jj) rm = fmaxf(rm, red[q][jj]);
    __syncthreads();                   // all reads of maxes done
    float ls = 0.f;
#pragma unroll 4
    for (int g = 0; g < 16; ++g) {
      float4 x = *(const float4*)&sc[q * 516 + j * 64 + 4 * g];
      x.x = __expf(x.x - rm); x.y = __expf(x.y - rm);
      x.z = __expf(x.z - rm); x.w = __expf(x.w - rm);
      *(float4*)&sc[q * 516 + j * 64 + 4 * g] = x;
      ls += x.x + x.y + x.z + x.w;
    }
    red[q][j] = ls;
    __syncthreads();
    if (j == 0) {                      // t < 32: q == t
      float tot = 0.f;
#pragma unroll
      for (int jj = 0; jj < 8; ++jj) tot += red[q][jj];
      red[q][8] = tot;
    }
  }
  // (no barrier needed yet: V staging below has its own)

  // ---- stage FULL VP panel into kb (phase-1 kb reads long done)
#pragma unroll 8
  for (int u = 0; u < 16; ++u) {
    const int r = srow + 32 * u;
    float4 v = *(const float4*)(vp + ((size_t)(b * 512 + r)) * 256 + h * 32 + scol4);
    *(float4*)KB4(kb, r, scol4) = v;
  }
  __syncthreads();

  // ---- Phase 3: ACC[q][a] = sum_k e[q][k]*vp[k][a]; thread = 8q x 4a,
  // 8-way k-split (64 k per slice).
  const int ag  = t & 7;               // a cols ag*4..+3
  const int qg3 = (t >> 3) & 3;        // q rows qg3+4r
  const int ks  = t >> 5;              // 0..7
  float a3[8][4] = {};
#pragma unroll 2
  for (int g = 0; g < 16; ++g) {
    const int kbase = ks * 64 + g * 4;
    float4 sq[8], vf[4];
#pragma unroll
    for (int r = 0; r < 8; ++r)
      sq[r] = *(const float4*)&sc[(qg3 + 4 * r) * 516 + kbase];
#pragma unroll
    for (int c = 0; c < 4; ++c)
      vf[c] = *(const float4*)KB4(kb, kbase + c, ag * 4);
#pragma unroll
    for (int r = 0; r < 8; ++r) {
      a3[r][0] += sq[r].x * vf[0].x + sq[r].y * vf[1].x + sq[r].z * vf[2].x + sq[r].w * vf[3].x;
      a3[r][1] += sq[r].x * vf[0].y + sq[r].y * vf[1].y + sq[r].z * vf[2].y + sq[r].w * vf[3].y;
      a3[r][2] += sq[r].x * vf[0].z + sq[r].y * vf[1].z + sq[r].z * vf[2].z + sq[r].w * vf[3].z;
      a3[r][3] += sq[r].x * vf[0].w + sq[r].y * vf[1].w + sq[r].z * vf[2].w + sq[r].w * vf[3].w;
    }
  }

  // ---- fold ks pair within wave (wave w holds ks = 2w, 2w+1)
#pragma unroll
  for (int r = 0; r < 8; ++r)
#pragma unroll
    for (int c = 0; c < 4; ++c)
      a3[r][c] += __shfl_xor(a3[r][c], 32);
  __syncthreads();                     // kb reads done; reuse as part
  float* part = &kb[0];                // [w4][32*36]
  if ((t & 32) == 0) {
    const int w = t >> 6;
#pragma unroll
    for (int r = 0; r < 8; ++r)
#pragma unroll
      for (int c = 0; c < 4; ++c)
        part[w * 1152 + (qg3 + 4 * r) * 36 + ag * 4 + c] = a3[r][c];
  }
  __syncthreads();

  // ---- final 4-wave reduction + robust power-mean epilogue (4 outputs/thr)
  {
    const int q = t >> 3, a0 = (t & 7) << 2;
    const int d0 = h * 32 + a0;
    const float invT = 1.0f / red[q][8];
    float4 s0 = *(const float4*)&part[q * 36 + a0];
    float4 s1 = *(const float4*)&part[1152 + q * 36 + a0];
    float4 s2 = *(const float4*)&part[2304 + q * 36 + a0];
    float4 s3 = *(const float4*)&part[3456 + q * 36 + a0];
    const float4 pp = *(const float4*)(pw + d0);
    const float4 vr = *(const float4*)(vrangew + b * 256 + d0);
    const float4 vm = *(const float4*)(vminw + b * 256 + d0);
    float4 o;
    o.x = (expf(log1pf((s0.x + s1.x + s2.x + s3.x) * invT) / pp.x) - BCONST) * vr.x / ONE_MINUS_B + vm.x;
    o.y = (expf(log1pf((s0.y + s1.y + s2.y + s3.y) * invT) / pp.y) - BCONST) * vr.y / ONE_MINUS_B + vm.y;
    o.z = (expf(log1pf((s0.z + s1.z + s2.z + s3.z) * invT) / pp.z) - BCONST) * vr.z / ONE_MINUS_B + vm.z;
    o.w = (expf(log1pf((s0.w + s1.w + s2.w + s3.w) * invT) / pp.w) - BCONST) * vr.w / ONE_MINUS_B + vm.w;
    *(float4*)(ew + ((size_t)(b * 512 + q0g + q)) * 256 + d0) = o;
  }
}

// ---------------------------------------------------------------------------
extern "C" void kernel_launch(void* const* d_in, const int* in_sizes, int n_in,
                              void* d_out, int out_size, void* d_ws, size_t ws_size,
                              hipStream_t stream) {
  const float* ctx  = (const float*)d_in[0];
  const float* WQ   = (const float*)d_in[1];
  const float* WKV  = (const float*)d_in[2];
  const float* WOUT = (const float*)d_in[3];
  const float* PP   = (const float*)d_in[4];
  float* ws      = (float*)d_ws;
  float* qkv     = ws + OFF_QKV;
  float* vp      = ws + OFF_VP;
  float* ew      = ws + OFF_EW;
  float* pminP   = ws + OFF_PMIN;
  float* pmaxP   = ws + OFF_PMAX;
  float* vminw   = ws + OFF_VMIN;
  float* vrangew = ws + OFF_VRANGE;
  float* pw      = ws + OFF_P;
  float* out     = (float*)d_out;

  // Fused Q|K|V projection + V min/max partials: 1024x768x256, 32x64 tiles
  gemm_t<32, 64, 2, 4, true><<<dim3(32, 12), 256, 0, stream>>>(
      ctx, WQ, WKV, 256, qkv, 768, 256, 256, pminP, pmaxP);
  // expm1(p * log(v_norm)) + p vector + vmin/vrange
  vpk<<<1024, 256, 0, stream>>>(qkv, pminP, pmaxP, PP, vp, vminw, vrangew, pw);
  // Fused attention + power-mean epilogue (32q blocks, 1 block/CU)
  attn_k<<<dim3(16, 16), 256, 0, stream>>>(qkv, vp, pw, vminw, vrangew, ew);
  // Output projection: 1024x256x256, 32x32 tiles
  gemm_t<32, 32, 2, 2, false><<<dim3(32, 8), 256, 0, stream>>>(
      ew, WOUT, WOUT, 1 << 30, out, 256, 256, 256, nullptr, nullptr);
}